// Round 12
// baseline (970.635 us; speedup 1.0000x reference)
//
#include <hip/hip_runtime.h>
#include <hip/hip_bf16.h>

typedef __bf16 bf16_t;
typedef float f32x4 __attribute__((ext_vector_type(4)));
typedef __bf16 bf16x8 __attribute__((ext_vector_type(8)));

#define ASYNC_COPY16(gptr, lptr) \
    __builtin_amdgcn_global_load_lds((const __attribute__((address_space(1))) void*)(gptr), \
                                     (__attribute__((address_space(3))) void*)(lptr), 16, 0, 0)

__device__ __forceinline__ float ldx(const void* p, long i, int isbf) {
    return isbf ? (float)((const bf16_t*)p)[i] : ((const float*)p)[i];
}

// ---------------- dtype probe ----------------
__global__ __launch_bounds__(256)
void detect_dtype(const void* __restrict__ x, int n, int* __restrict__ flags)
{
    __shared__ int red[4];
    const int tid = threadIdx.x;
    const int ns = n < 8192 ? n : 8192;
    int cnt = 0;
    for (int i = tid; i < ns; i += 256) {
        float v = (float)((const bf16_t*)x)[i];
        float a = fabsf(v);
        bool pl = (v == 0.f) || (a >= 6e-8f && a <= 1.7e7f);
        cnt += pl ? 1 : 0;
    }
    for (int o = 32; o; o >>= 1) cnt += __shfl_down(cnt, o);
    if ((tid & 63) == 0) red[tid >> 6] = cnt;
    __syncthreads();
    if (tid == 0) {
        int t = red[0] + red[1] + red[2] + red[3];
        flags[0] = (t * 10 >= ns * 9) ? 1 : 0;
    }
}

struct C3 { const void* p[3]; bf16_t* d[3]; int n[3]; };
__global__ __launch_bounds__(256)
void conv_elem3(C3 c, const int* __restrict__ flag)
{
    const int isbf = *flag;
    const int z = blockIdx.z, n = c.n[z];
    bf16_t* dst = c.d[z];
    const void* src = c.p[z];
    for (long i = blockIdx.x * 256L + threadIdx.x; i < n; i += (long)gridDim.x * 256)
        dst[i] = (bf16_t)ldx(src, i, isbf);
}

struct P9 { const void* p[9]; int n[9]; };
__global__ __launch_bounds__(256)
void conv_param(P9 pk, float* __restrict__ dst, const int* __restrict__ flag)
{
    const int isbf = *flag;
    const int b = blockIdx.x, n = pk.n[b];
    for (int j = threadIdx.x; j < n; j += 256)
        dst[b * 544 + j] = ldx(pk.p[b], j, isbf);
}

struct P3 { const void* p[3]; };
__global__ __launch_bounds__(256)
void pad_wf3(P3 ps, bf16_t* __restrict__ Wp0, const int* __restrict__ flag)
{
    const int isbf = *flag;
    const int z = blockIdx.z;
    const long i = blockIdx.x * 256L + threadIdx.x;
    if (i >= 512 * 544) return;
    const long o = i / 544, c = i % 544;
    bf16_t* Wp = Wp0 + (size_t)z * 512 * 544;
    Wp[i] = (c < 515) ? (bf16_t)ldx(ps.p[z], o * 515 + c, isbf) : (bf16_t)0.f;
}

// ---- X (512x2048) -> XtA[n][hi|lo|hi], XtB[n][hi|hi|lo] (2048x1536 bf16) ----
__global__ __launch_bounds__(256)
void transpose_split(const void* __restrict__ X, bf16_t* __restrict__ XtA,
                     bf16_t* __restrict__ XtB, const int* __restrict__ flag)
{
    __shared__ __align__(16) bf16_t thi[32][33];
    __shared__ __align__(16) bf16_t tlo[32][33];
    const int isbf = *flag;
    const int n0 = blockIdx.x * 32, c0 = blockIdx.y * 32;
    const int lx = threadIdx.x & 31, ly = threadIdx.x >> 5;
    for (int i = 0; i < 4; ++i) {
        float v = ldx(X, (long)(c0 + ly + i * 8) * 2048 + n0 + lx, isbf);
        bf16_t hi = (bf16_t)v;
        thi[ly + i * 8][lx] = hi;
        tlo[ly + i * 8][lx] = (bf16_t)(v - (float)hi);
    }
    __syncthreads();
    for (int i = 0; i < 4; ++i) {
        const long n = n0 + ly + i * 8;
        const int c = c0 + lx;
        bf16_t hi = thi[lx][ly + i * 8], lo = tlo[lx][ly + i * 8];
        XtA[n * 1536 + c] = hi;  XtA[n * 1536 + 512 + c] = lo;  XtA[n * 1536 + 1024 + c] = hi;
        XtB[n * 1536 + c] = hi;  XtB[n * 1536 + 512 + c] = hi;  XtB[n * 1536 + 1024 + c] = lo;
    }
}

__global__ __launch_bounds__(256)
void xx_kernel(const bf16_t* __restrict__ XtA, float* __restrict__ xx)
{
    const long n = blockIdx.x * 256L + threadIdx.x;
    float acc = 0.f;
    for (int c = 0; c < 512; ++c) {
        float v = (float)XtA[n * 1536 + c] + (float)XtA[n * 1536 + 512 + c];
        acc += v * v;
    }
    xx[n] = acc;
}

// ======== conv6: 128x128 BARRIER-FREE register-direct MFMA GEMM ========
// No LDS, no __syncthreads in K-loop: each wave global_load_dwordx4's its own
// A/B fragments into VGPRs (frag layout row=l15, k=quad*8). Kills the per-iter
// vmcnt(0) barrier drain that capped the LDS version at MfmaUtil 14%.
// 2x intra-block read redundancy is absorbed by L2 (W6 resident; H shared via
// XCD swizzle: the 5 m-tiles of one n-tile land on one XCD -> B streamed once).
// Same k0 accumulation order as gemm128d -> bit-identical C2c.
__global__ __launch_bounds__(256)
void gemm128r(const bf16_t* __restrict__ A, const bf16_t* __restrict__ B,
              float* __restrict__ C, int M, int N, int K, int lda, int ldb, int ldc)
{
    const int tid = threadIdx.x;
    int mt, nt;
    if ((gridDim.y & 7) == 0) {
        const int bid = blockIdx.y * gridDim.x + blockIdx.x;
        const int xcd = bid & 7, s = bid >> 3;
        mt = s % gridDim.x;
        nt = xcd + 8 * (s / gridDim.x);
    } else { mt = blockIdx.x; nt = blockIdx.y; }
    const int m0 = mt * 128, n0 = nt * 128;
    const int wave = tid >> 6, lane = tid & 63;
    const int wm = (wave >> 1) * 64, wn = (wave & 1) * 64;
    const int l15 = lane & 15, quad = lane >> 4;

    // per-lane fragment base pointers (k advances by +32 each step)
    const bf16_t* ap[4];
    const bf16_t* bp[4];
    for (int mi = 0; mi < 4; ++mi) {
        long r = min((long)(m0 + wm + mi * 16 + l15), (long)M - 1);
        ap[mi] = A + r * lda + quad * 8;
    }
    for (int ni = 0; ni < 4; ++ni) {
        long r = min((long)(n0 + wn + ni * 16 + l15), (long)N - 1);
        bp[ni] = B + r * ldb + quad * 8;
    }

    f32x4 acc[4][4] = {};
    bf16x8 a0[4], b0[4], a1[4], b1[4];

    // prologue: k=0 fragments
    for (int i = 0; i < 4; ++i) { a0[i] = *(const bf16x8*)(ap[i]); b0[i] = *(const bf16x8*)(bp[i]); }

    // K multiple of 64 (2048): unroll-2 software pipeline, no barriers
    for (int k0 = 0; k0 < K; k0 += 64) {
        for (int i = 0; i < 4; ++i) {
            a1[i] = *(const bf16x8*)(ap[i] + k0 + 32);
            b1[i] = *(const bf16x8*)(bp[i] + k0 + 32);
        }
        for (int mi = 0; mi < 4; ++mi)
        for (int ni = 0; ni < 4; ++ni)
            acc[mi][ni] = __builtin_amdgcn_mfma_f32_16x16x32_bf16(a0[mi], b0[ni], acc[mi][ni], 0, 0, 0);
        if (k0 + 64 < K) {
            for (int i = 0; i < 4; ++i) {
                a0[i] = *(const bf16x8*)(ap[i] + k0 + 64);
                b0[i] = *(const bf16x8*)(bp[i] + k0 + 64);
            }
        }
        for (int mi = 0; mi < 4; ++mi)
        for (int ni = 0; ni < 4; ++ni)
            acc[mi][ni] = __builtin_amdgcn_mfma_f32_16x16x32_bf16(a1[mi], b1[ni], acc[mi][ni], 0, 0, 0);
    }

    for (int mi = 0; mi < 4; ++mi)
    for (int ni = 0; ni < 4; ++ni)
    for (int r = 0; r < 4; ++r) {
        int gm = m0 + wm + mi * 16 + quad * 4 + r;
        int gn = n0 + wn + ni * 16 + l15;
        if (gm >= M || gn >= N) continue;
        C[(long)gm * ldc + gn] = acc[mi][ni][r];
    }
}

// --- f[c0+cl, o2] = max_k lrelu(bn6(C2c[o2, cl*40+k])), padded bf16 [512][544] ---
__global__ __launch_bounds__(256)
void epi6_max(const float* __restrict__ C2c, const float* __restrict__ p6,
              bf16_t* __restrict__ Fb, int c0, int Nc)
{
    const int cl = blockIdx.x, tid = threadIdx.x;
    for (int o2 = tid; o2 < 544; o2 += 256) {
        float r = 0.f;
        if (o2 < 515) {
            const float sc = p6[o2] / sqrtf(p6[3 * 544 + o2] + 1e-5f);
            const float mu = p6[2 * 544 + o2], bb = p6[1 * 544 + o2];
            const float4* p = (const float4*)(C2c + (long)o2 * Nc + cl * 40);
            float mx = -__builtin_inff();
            for (int k4 = 0; k4 < 10; ++k4) {
                float4 v = p[k4];
                float hv[4] = {v.x, v.y, v.z, v.w};
                for (int j = 0; j < 4; ++j) {
                    float h = (hv[j] - mu) * sc + bb;
                    h = h >= 0.f ? h : 0.2f * h;
                    mx = fmaxf(mx, h);
                }
            }
            r = mx;
        }
        Fb[(long)(c0 + cl) * 544 + o2] = (bf16_t)r;
    }
}

// ======== 64x64x32 dbuf async GEMM (kNN / T-U) ========
__global__ __launch_bounds__(256)
void gemm64d(const bf16_t* __restrict__ A, const bf16_t* __restrict__ B,
             float* __restrict__ C, const float* __restrict__ xx,
             int M, int N, int K, int lda, int ldb, int ldc,
             long aBS, long bBS, long cBS, int epi, int moff)
{
    __shared__ __align__(16) bf16_t As[2][4 * 64 * 8];
    __shared__ __align__(16) bf16_t Bs[2][4 * 64 * 8];
    const int tid = threadIdx.x;
    const int m0 = blockIdx.y * 64, n0 = blockIdx.x * 64;
    if (epi == 4 && n0 < m0) return;   // symmetric: upper-triangle blocks only
    const int bz = blockIdx.z;
    A += (long)bz * aBS;
    B += (long)bz * bBS;
    const int wave = tid >> 6, lane = tid & 63;
    const int wm = (wave >> 1) * 32, wn = (wave & 1) * 32;
    const int l15 = lane & 15, quad = lane >> 4;

    const long ar = min((long)(m0 + lane), (long)M - 1);
    const long br = min((long)(n0 + lane), (long)N - 1);
    const bf16_t* ga = A + ar * lda + wave * 8;
    const bf16_t* gb = B + br * ldb + wave * 8;

    f32x4 acc[2][2] = {};

    ASYNC_COPY16(ga, &As[0][wave * 512]);
    ASYNC_COPY16(gb, &Bs[0][wave * 512]);

    for (int k0 = 0; k0 < K; k0 += 32) {
        const int cur = (k0 >> 5) & 1;
        __syncthreads();
        if (k0 + 32 < K) {
            ASYNC_COPY16(ga + k0 + 32, &As[cur ^ 1][wave * 512]);
            ASYNC_COPY16(gb + k0 + 32, &Bs[cur ^ 1][wave * 512]);
        }
        bf16x8 af0 = *(const bf16x8*)&As[cur][quad * 512 + (wm +      l15) * 8];
        bf16x8 af1 = *(const bf16x8*)&As[cur][quad * 512 + (wm + 16 + l15) * 8];
        bf16x8 bf0 = *(const bf16x8*)&Bs[cur][quad * 512 + (wn +      l15) * 8];
        bf16x8 bf1 = *(const bf16x8*)&Bs[cur][quad * 512 + (wn + 16 + l15) * 8];
        acc[0][0] = __builtin_amdgcn_mfma_f32_16x16x32_bf16(af0, bf0, acc[0][0], 0, 0, 0);
        acc[0][1] = __builtin_amdgcn_mfma_f32_16x16x32_bf16(af0, bf1, acc[0][1], 0, 0, 0);
        acc[1][0] = __builtin_amdgcn_mfma_f32_16x16x32_bf16(af1, bf0, acc[1][0], 0, 0, 0);
        acc[1][1] = __builtin_amdgcn_mfma_f32_16x16x32_bf16(af1, bf1, acc[1][1], 0, 0, 0);
    }

    C += (long)bz * cBS;
    for (int mi = 0; mi < 2; ++mi)
    for (int ni = 0; ni < 2; ++ni)
    for (int r = 0; r < 4; ++r) {
        int gm = m0 + wm + mi * 16 + quad * 4 + r;
        int gn = n0 + wn + ni * 16 + l15;
        if (gm >= M || gn >= N) continue;
        float o = acc[mi][ni][r];
        if (epi == 4) {
            float v = 2.f * o - xx[gm] - xx[gn];
            C[(long)gm * ldc + gn] = v;
            C[(long)gn * ldc + gm] = v;
        } else if (epi == 1) {
            C[(long)gm * ldc + gn] = 2.f * o - xx[gm + moff] - xx[gn];
        } else {
            C[(long)gm * ldc + gn] = o;
        }
    }
}

// ---------------- 64-tile sync NT GEMM (small mats / rich epilogues) ----------------
__global__ __launch_bounds__(256)
void gemm_nt(const bf16_t* __restrict__ A, const bf16_t* __restrict__ B,
             void* __restrict__ Cv, const float* __restrict__ bias,
             const int* __restrict__ oflag, float alpha,
             int M, int N, int K, int lda, int ldb, int ldc,
             long aBS, long bBS, long cBS, int epi)
{
    __shared__ __align__(16) bf16_t As[64 * 40];
    __shared__ __align__(16) bf16_t Bs[64 * 40];
    const int tid = threadIdx.x;
    const int m0 = blockIdx.y * 64, n0 = blockIdx.x * 64;
    const int bz = blockIdx.z;
    A += (long)bz * aBS;
    B += (long)bz * bBS;

    const int lrow = tid >> 2;
    const int lseg = (tid & 3) * 8;
    const long arow = min(m0 + lrow, M - 1);
    const long brow = min(n0 + lrow, N - 1);
    const bf16_t* ap = A + arow * lda + lseg;
    const bf16_t* bp = B + brow * ldb + lseg;

    const int wave = tid >> 6, lane = tid & 63;
    const int wm = (wave >> 1) * 32, wn = (wave & 1) * 32;
    const int l15 = lane & 15, quad = lane >> 4;

    f32x4 acc[2][2] = {};

    for (int k0 = 0; k0 < K; k0 += 32) {
        int4 av = *(const int4*)ap;  ap += 32;
        int4 bv = *(const int4*)bp;  bp += 32;
        __syncthreads();
        *(int4*)(&As[lrow * 40 + lseg]) = av;
        *(int4*)(&Bs[lrow * 40 + lseg]) = bv;
        __syncthreads();
        bf16x8 af0 = *(const bf16x8*)(&As[(wm +      l15) * 40 + quad * 8]);
        bf16x8 af1 = *(const bf16x8*)(&As[(wm + 16 + l15) * 40 + quad * 8]);
        bf16x8 bf0 = *(const bf16x8*)(&Bs[(wn +      l15) * 40 + quad * 8]);
        bf16x8 bf1 = *(const bf16x8*)(&Bs[(wn + 16 + l15) * 40 + quad * 8]);
        acc[0][0] = __builtin_amdgcn_mfma_f32_16x16x32_bf16(af0, bf0, acc[0][0], 0, 0, 0);
        acc[0][1] = __builtin_amdgcn_mfma_f32_16x16x32_bf16(af0, bf1, acc[0][1], 0, 0, 0);
        acc[1][0] = __builtin_amdgcn_mfma_f32_16x16x32_bf16(af1, bf0, acc[1][0], 0, 0, 0);
        acc[1][1] = __builtin_amdgcn_mfma_f32_16x16x32_bf16(af1, bf1, acc[1][1], 0, 0, 0);
    }

    const int ofl = oflag ? *oflag : 1;
    for (int mi = 0; mi < 2; ++mi)
    for (int ni = 0; ni < 2; ++ni)
    for (int r = 0; r < 4; ++r) {
        int gm = m0 + wm + mi * 16 + quad * 4 + r;
        int gn = n0 + wn + ni * 16 + l15;
        if (gm >= M || gn >= N) continue;
        float o = acc[mi][ni][r];
        long cidx = (long)bz * cBS + (long)gm * ldc + gn;
        switch (epi) {
        case 2: ((bf16_t*)Cv)[cidx] = (bf16_t)o; break;
        case 3: ((float*)Cv)[cidx] = o * alpha; break;
        case 5: ((bf16_t*)Cv)[(long)bz * cBS + (long)gn * ldc + gm] = (bf16_t)o; break;
        case 6: {
            float w = o + bias[gn];
            if (ofl) ((bf16_t*)Cv)[cidx] = (bf16_t)w;
            else     ((float*)Cv)[cidx]  = w;
        } break;
        }
    }
}

// ======== binary-search top-40, SORTED emission (matches lax.top_k order exactly) ========
__global__ __launch_bounds__(256)
void topk40_bs(const float* __restrict__ S, int* __restrict__ idx_out)
{
    __shared__ int red[4];
    __shared__ unsigned long long tmask[8][4];
    __shared__ int sh_slot;
    __shared__ unsigned cu[48];
    __shared__ int      ci[48];
    const int row = blockIdx.x, tid = threadIdx.x;
    const int wave = tid >> 6, lane = tid & 63;

    unsigned uvr[8];
    for (int c = 0; c < 8; ++c) {
        unsigned x = __float_as_uint(S[(long)row * 2048 + c * 256 + tid]);
        uvr[c] = (x & 0x80000000u) ? ~x : (x | 0x80000000u);
    }
    if (tid == 0) sh_slot = 0;

    unsigned lo = 0u, hi = 0xFFFFFFFFu;
    while (hi - lo > 1u) {
        unsigned mid = lo + ((hi - lo) >> 1);
        int c = 0;
        for (int i = 0; i < 8; ++i) c += (uvr[i] > mid) ? 1 : 0;
        for (int o = 32; o; o >>= 1) c += __shfl_down(c, o);
        if (lane == 0) red[wave] = c;
        __syncthreads();
        int tot = red[0] + red[1] + red[2] + red[3];
        __syncthreads();
        if (tot >= 40) lo = mid; else hi = mid;
    }
    const unsigned thr = hi;

    for (int c = 0; c < 8; ++c)
        if (uvr[c] > thr) {
            int s = atomicAdd(&sh_slot, 1);
            cu[s] = uvr[c]; ci[s] = c * 256 + tid;
        }
    for (int c = 0; c < 8; ++c) {
        unsigned long long m = __ballot(uvr[c] == thr);
        if (lane == 0) tmask[c][wave] = m;
    }
    __syncthreads();
    const int want = 40 - sh_slot;
    int base = 0;
    for (int c = 0; c < 8; ++c) {
        if (uvr[c] == thr) {
            int r = base;
            for (int w = 0; w < wave; ++w) r += __popcll(tmask[c][w]);
            r += __popcll(tmask[c][wave] & (((unsigned long long)1 << lane) - 1));
            if (r < want) {
                int s = atomicAdd(&sh_slot, 1);
                cu[s] = uvr[c]; ci[s] = c * 256 + tid;
            }
        }
        for (int w = 0; w < 4; ++w) base += __popcll(tmask[c][w]);
    }
    __syncthreads();
    if (tid < 40) {
        unsigned u = cu[tid]; int i = ci[tid];
        int r = 0;
        for (int j = 0; j < 40; ++j)
            r += (cu[j] > u || (cu[j] == u && ci[j] < i)) ? 1 : 0;
        idx_out[row * 40 + r] = i;
    }
}

// --- H-chunk: Hc[((c5-c0)*40+k)*2048+n] = bf16(lrelu(bn5(T[c5,idx[n,k]] + (U-T)[c5,n]))) ---
__global__ __launch_bounds__(256)
void h1a_gen(const float* __restrict__ T, const float* __restrict__ U,
             const int* __restrict__ idx, const float* __restrict__ pf,
             bf16_t* __restrict__ Hc, int c0)
{
    __shared__ int idxs[40 * 256];
    const int c5 = c0 + blockIdx.y, n0 = blockIdx.x * 256, tid = threadIdx.x;
    for (int i = tid; i < 40 * 256; i += 256)
        idxs[(i % 40) * 256 + (i / 40)] = idx[n0 * 40 + i] & 2047;
    const float sc = pf[c5] / sqrtf(pf[3 * 544 + c5] + 1e-5f);
    const float mu = pf[2 * 544 + c5], bb = pf[1 * 544 + c5];
    const float q  = U[(long)c5 * 2048 + n0 + tid] - T[(long)c5 * 2048 + n0 + tid];
    const float* Trow = T + (long)c5 * 2048;
    __syncthreads();
    for (int k = 0; k < 40; ++k) {
        float h = Trow[idxs[k * 256 + tid]] + q;
        h = (h - mu) * sc + bb;
        h = h >= 0.f ? h : 0.2f * h;
        Hc[(long)(blockIdx.y * 40 + k) * 2048 + n0 + tid] = (bf16_t)h;
    }
}

__global__ __launch_bounds__(256)
void softmax_row(const float* __restrict__ Sc, bf16_t* __restrict__ P)
{
    __shared__ float red[4];
    const long r = blockIdx.x;
    const int tid = threadIdx.x, lane = tid & 63, wave = tid >> 6;
    const float* row = Sc + r * 512;
    float v0 = row[tid], v1 = row[tid + 256];
    float mx = fmaxf(v0, v1);
    for (int off = 32; off; off >>= 1) mx = fmaxf(mx, __shfl_down(mx, off));
    if (lane == 0) red[wave] = mx;
    __syncthreads();
    mx = fmaxf(fmaxf(red[0], red[1]), fmaxf(red[2], red[3]));
    __syncthreads();
    float e0 = expf(v0 - mx), e1 = expf(v1 - mx);
    float sm = e0 + e1;
    for (int off = 32; off; off >>= 1) sm += __shfl_down(sm, off);
    if (lane == 0) red[wave] = sm;
    __syncthreads();
    sm = red[0] + red[1] + red[2] + red[3];
    float inv = 1.f / sm;
    P[r * 512 + tid] = (bf16_t)(e0 * inv);
    P[r * 512 + tid + 256] = (bf16_t)(e1 * inv);
}

extern "C" void kernel_launch(void* const* d_in, const int* in_sizes, int n_in,
                              void* d_out, int out_size, void* d_ws, size_t ws_size,
                              hipStream_t stream)
{
    (void)n_in; (void)out_size;

    char* wsb = (char*)d_ws;
    size_t pos = 0;
    auto alloc = [&](size_t bytes) -> char* {
        char* p = wsb + pos;
        pos += (bytes + 255) & ~(size_t)255;
        return p;
    };
    int*    flags = (int*)  alloc(256);
    int*    idx   = (int*)  alloc(2048 * 40 * 4);
    float*  xx    = (float*)alloc(2048 * 4);
    float*  T     = (float*)alloc((size_t)512 * 2048 * 4);   // U follows contiguously
    float*  U     = (float*)alloc((size_t)512 * 2048 * 4);
    bf16_t* XtA   = (bf16_t*)alloc((size_t)2048 * 1536 * 2);
    bf16_t* XtB   = (bf16_t*)alloc((size_t)2048 * 1536 * 2);
    bf16_t* W5c   = (bf16_t*)alloc((size_t)512 * 1024 * 2);
    bf16_t* W6c   = (bf16_t*)alloc((size_t)515 * 2048 * 2);
    bf16_t* Woutc = (bf16_t*)alloc((size_t)515 * 512 * 2);
    bf16_t* Wqp   = (bf16_t*)alloc((size_t)512 * 544 * 2);
    bf16_t* Wkp   = (bf16_t*)alloc((size_t)512 * 544 * 2);
    bf16_t* Wvp   = (bf16_t*)alloc((size_t)512 * 544 * 2);
    float*  pf    = (float*)alloc((size_t)9 * 544 * 4);
    bf16_t* Fb[2];
    Fb[0] = (bf16_t*)alloc((size_t)512 * 544 * 2);
    Fb[1] = (bf16_t*)alloc((size_t)512 * 544 * 2);
    bf16_t* qb = (bf16_t*)alloc((size_t)512 * 512 * 2);
    bf16_t* kb = (bf16_t*)alloc((size_t)512 * 512 * 2);
    bf16_t* vt = (bf16_t*)alloc((size_t)512 * 512 * 2);
    bf16_t* mg = (bf16_t*)alloc((size_t)512 * 512 * 2);
    char* BIG = wsb + pos;
    size_t big = (ws_size > pos) ? (ws_size - pos) : 0;
    if (big < 3939840) return;

    const int CC = (big >= 126074880) ? 512 : (big >= 63037440) ? 256
                 : (big >= 31518720)  ? 128 : (big >= 15759360) ? 64
                 : (big >= 7879680)   ? 32  : 16;
    const int RC = (big >= 16777216) ? 2048 : (big >= 4194304) ? 512 : 128;
    const int AH = (big >= 12582912) ? 8 : 1;
    const int Nc = CC * 40;

    float*  S   = (float*)BIG;
    bf16_t* Hc  = (bf16_t*)BIG;
    float*  C2c = (float*)(BIG + (size_t)Nc * 2048 * 2);
    float*  scA = (float*)BIG;
    bf16_t* prA = (bf16_t*)(BIG + (size_t)AH * 512 * 512 * 4);

    detect_dtype<<<1, 256, 0, stream>>>(d_in[0], in_sizes[0], flags);
    C3 c3;
    c3.p[0] = d_in[2];  c3.d[0] = W5c;   c3.n[0] = 512 * 1024;
    c3.p[1] = d_in[7];  c3.d[1] = W6c;   c3.n[1] = 515 * 2048;
    c3.p[2] = d_in[15]; c3.d[2] = Woutc; c3.n[2] = 515 * 512;
    conv_elem3<<<dim3(512, 1, 3), 256, 0, stream>>>(c3, flags);
    P3 p3;
    p3.p[0] = d_in[12]; p3.p[1] = d_in[13]; p3.p[2] = d_in[14];
    pad_wf3<<<dim3(1088, 1, 3), 256, 0, stream>>>(p3, Wqp, flags);
    P9 pk;
    const int pidx[9] = {3, 4, 5, 6, 8, 9, 10, 11, 16};
    for (int i = 0; i < 9; ++i) { pk.p[i] = d_in[pidx[i]]; pk.n[i] = in_sizes[pidx[i]]; }
    conv_param<<<9, 256, 0, stream>>>(pk, pf, flags);

    for (int b = 0; b < 2; ++b) {
        transpose_split<<<dim3(64, 16), 256, 0, stream>>>(d_in[b], XtA, XtB, flags);
        xx_kernel<<<8, 256, 0, stream>>>(XtA, xx);
        if (RC == 2048) {
            gemm64d<<<dim3(32, 32), 256, 0, stream>>>(XtA, XtB, S,
                xx, 2048, 2048, 1536, 1536, 1536, 2048, 0, 0, 0, 4, 0);
            topk40_bs<<<2048, 256, 0, stream>>>(S, idx);
        } else {
            for (int r0 = 0; r0 < 2048; r0 += RC) {
                gemm64d<<<dim3(32, RC / 64), 256, 0, stream>>>(XtA + (size_t)r0 * 1536, XtB, S,
                    xx, RC, 2048, 1536, 1536, 1536, 2048, 0, 0, 0, 1, r0);
                topk40_bs<<<RC, 256, 0, stream>>>(S, idx + (size_t)r0 * 40);
            }
        }
        gemm64d<<<dim3(32, 8, 2), 256, 0, stream>>>(W5c, XtA, T, nullptr,
            512, 2048, 512, 1024, 1536, 2048, 512, 0, (long)512 * 2048, 0, 0);
        for (int c0 = 0; c0 < 512; c0 += CC) {
            h1a_gen<<<dim3(8, CC), 256, 0, stream>>>(T, U, idx, pf, Hc, c0);
            gemm128r<<<dim3(5, Nc / 128), 256, 0, stream>>>(W6c, Hc, C2c,
                515, Nc, 2048, 2048, 2048, Nc);
            epi6_max<<<CC, 256, 0, stream>>>(C2c, pf + 4 * 544, Fb[b], c0, Nc);
        }
    }

    gemm_nt<<<dim3(8, 8, 2), 256, 0, stream>>>(Fb[0], Wqp, qb, nullptr, nullptr, 0.f,
        512, 512, 544, 544, 544, 512,
        (long)512 * 544, (long)512 * 544, (long)512 * 512, 2);
    gemm_nt<<<dim3(8, 8, 1), 256, 0, stream>>>(Fb[1], Wvp, vt, nullptr, nullptr, 0.f,
        512, 512, 544, 544, 544, 512, 0, 0, 0, 5);

    const float SCALE = 0.04419417382415922f;  // 512^-0.5
    if (AH == 8) {
        gemm_nt<<<dim3(8, 8, 8), 256, 0, stream>>>(qb, kb, scA, nullptr, nullptr, SCALE,
            512, 512, 64, 512, 512, 512, 64, 64, 262144, 3);
        softmax_row<<<4096, 256, 0, stream>>>(scA, prA);
        gemm_nt<<<dim3(1, 8, 8), 256, 0, stream>>>(prA, vt, mg, nullptr, nullptr, 0.f,
            512, 64, 512, 512, 512, 512, 262144, 32768, 64, 2);
    } else {
        for (int h = 0; h < 8; ++h) {
            gemm_nt<<<dim3(8, 8, 1), 256, 0, stream>>>(qb + h * 64, kb + h * 64, scA,
                nullptr, nullptr, SCALE, 512, 512, 64, 512, 512, 512, 0, 0, 0, 3);
            softmax_row<<<512, 256, 0, stream>>>(scA, prA);
            gemm_nt<<<dim3(1, 8, 1), 256, 0, stream>>>(prA, vt + (size_t)h * 64 * 512,
                mg + h * 64, nullptr, nullptr, 0.f,
                512, 64, 512, 512, 512, 512, 0, 0, 0, 2);
        }
    }
    gemm_nt<<<dim3(9, 8, 1), 256, 0, stream>>>(mg, Woutc, d_out, pf + 8 * 544, flags,
        0.f, 512, 515, 512, 512, 512, 515, 0, 0, 0, 6);
}

// Round 13
// 872.201 us; speedup vs baseline: 1.1129x; 1.1129x over previous
//
#include <hip/hip_runtime.h>
#include <hip/hip_bf16.h>

typedef __bf16 bf16_t;
typedef float f32x4 __attribute__((ext_vector_type(4)));
typedef __bf16 bf16x8 __attribute__((ext_vector_type(8)));
typedef __bf16 bf16x4 __attribute__((ext_vector_type(4)));

#define ASYNC_COPY16(gptr, lptr) \
    __builtin_amdgcn_global_load_lds((const __attribute__((address_space(1))) void*)(gptr), \
                                     (__attribute__((address_space(3))) void*)(lptr), 16, 0, 0)

__device__ __forceinline__ float ldx(const void* p, long i, int isbf) {
    return isbf ? (float)((const bf16_t*)p)[i] : ((const float*)p)[i];
}

// ---------------- dtype probe ----------------
__global__ __launch_bounds__(256)
void detect_dtype(const void* __restrict__ x, int n, int* __restrict__ flags)
{
    __shared__ int red[4];
    const int tid = threadIdx.x;
    const int ns = n < 8192 ? n : 8192;
    int cnt = 0;
    for (int i = tid; i < ns; i += 256) {
        float v = (float)((const bf16_t*)x)[i];
        float a = fabsf(v);
        bool pl = (v == 0.f) || (a >= 6e-8f && a <= 1.7e7f);
        cnt += pl ? 1 : 0;
    }
    for (int o = 32; o; o >>= 1) cnt += __shfl_down(cnt, o);
    if ((tid & 63) == 0) red[tid >> 6] = cnt;
    __syncthreads();
    if (tid == 0) {
        int t = red[0] + red[1] + red[2] + red[3];
        flags[0] = (t * 10 >= ns * 9) ? 1 : 0;
    }
}

struct C3 { const void* p[3]; bf16_t* d[3]; int n[3]; };
__global__ __launch_bounds__(256)
void conv_elem3(C3 c, const int* __restrict__ flag)
{
    const int isbf = *flag;
    const int z = blockIdx.z, n = c.n[z];
    bf16_t* dst = c.d[z];
    const void* src = c.p[z];
    for (long i = blockIdx.x * 256L + threadIdx.x; i < n; i += (long)gridDim.x * 256)
        dst[i] = (bf16_t)ldx(src, i, isbf);
}

struct P9 { const void* p[9]; int n[9]; };
__global__ __launch_bounds__(256)
void conv_param(P9 pk, float* __restrict__ dst, const int* __restrict__ flag)
{
    const int isbf = *flag;
    const int b = blockIdx.x, n = pk.n[b];
    for (int j = threadIdx.x; j < n; j += 256)
        dst[b * 544 + j] = ldx(pk.p[b], j, isbf);
}

struct P3 { const void* p[3]; };
__global__ __launch_bounds__(256)
void pad_wf3(P3 ps, bf16_t* __restrict__ Wp0, const int* __restrict__ flag)
{
    const int isbf = *flag;
    const int z = blockIdx.z;
    const long i = blockIdx.x * 256L + threadIdx.x;
    if (i >= 512 * 544) return;
    const long o = i / 544, c = i % 544;
    bf16_t* Wp = Wp0 + (size_t)z * 512 * 544;
    Wp[i] = (c < 515) ? (bf16_t)ldx(ps.p[z], o * 515 + c, isbf) : (bf16_t)0.f;
}

// ---- X (512x2048) -> XtA[n][hi|lo|hi], XtB[n][hi|hi|lo] (2048x1536 bf16) ----
__global__ __launch_bounds__(256)
void transpose_split(const void* __restrict__ X, bf16_t* __restrict__ XtA,
                     bf16_t* __restrict__ XtB, const int* __restrict__ flag)
{
    __shared__ __align__(16) bf16_t thi[32][33];
    __shared__ __align__(16) bf16_t tlo[32][33];
    const int isbf = *flag;
    const int n0 = blockIdx.x * 32, c0 = blockIdx.y * 32;
    const int lx = threadIdx.x & 31, ly = threadIdx.x >> 5;
    for (int i = 0; i < 4; ++i) {
        float v = ldx(X, (long)(c0 + ly + i * 8) * 2048 + n0 + lx, isbf);
        bf16_t hi = (bf16_t)v;
        thi[ly + i * 8][lx] = hi;
        tlo[ly + i * 8][lx] = (bf16_t)(v - (float)hi);
    }
    __syncthreads();
    for (int i = 0; i < 4; ++i) {
        const long n = n0 + ly + i * 8;
        const int c = c0 + lx;
        bf16_t hi = thi[lx][ly + i * 8], lo = tlo[lx][ly + i * 8];
        XtA[n * 1536 + c] = hi;  XtA[n * 1536 + 512 + c] = lo;  XtA[n * 1536 + 1024 + c] = hi;
        XtB[n * 1536 + c] = hi;  XtB[n * 1536 + 512 + c] = hi;  XtB[n * 1536 + 1024 + c] = lo;
    }
}

__global__ __launch_bounds__(256)
void xx_kernel(const bf16_t* __restrict__ XtA, float* __restrict__ xx)
{
    const long n = blockIdx.x * 256L + threadIdx.x;
    float acc = 0.f;
    for (int c = 0; c < 512; ++c) {
        float v = (float)XtA[n * 1536 + c] + (float)XtA[n * 1536 + 512 + c];
        acc += v * v;
    }
    xx[n] = acc;
}

// ======== conv6: 128x128x32 dbuf LDS GEMM (R10-proven), XCD-swizzled, M-trimmed ========
// Grid x = 4 m-tiles (rows 0-511, no dead 5th tile: was 19.5% wasted blocks).
// mt==3 blocks additionally stage rows 512-527 (clamped) into As2 (+1 KB LDS, one extra
// global_load_lds) and waves wm==64 run a 5th MFMA row-group for o2 512-514.
// Output C2 stored as bf16 (feeds bn6~identity -> lrelu -> max -> bf16 Fb anyway):
// halves C2c write + epi6 read traffic. Same k0 accumulation order as R10/R11.
__global__ __launch_bounds__(256)
void gemm128d(const bf16_t* __restrict__ A, const bf16_t* __restrict__ B,
              bf16_t* __restrict__ C, int M, int N, int K, int lda, int ldb, int ldc)
{
    __shared__ __align__(16) bf16_t As[2][4096];   // [stage][seg(4)][row(128)][8]
    __shared__ __align__(16) bf16_t Bs[2][4096];
    __shared__ __align__(16) bf16_t As2[2][512];   // [stage][seg(4)][row(16)][8]
    const int tid = threadIdx.x;
    int mt, nt;
    {   // XCD swizzle (proven R9/R10: FETCH 250->73 MB): gridDim.y multiple of 8
        const int bid = blockIdx.y * gridDim.x + blockIdx.x;
        const int xcd = bid & 7, s = bid >> 3;
        mt = s % gridDim.x;
        nt = xcd + 8 * (s / gridDim.x);
    }
    const int m0 = mt * 128, n0 = nt * 128;
    const int wave = tid >> 6, lane = tid & 63;
    const int wm = (wave >> 1) * 64, wn = (wave & 1) * 64;
    const int l15 = lane & 15, quad = lane >> 4;
    const bool xrows = (mt == 3);                  // this block also handles rows 512..514

    const bf16_t* ga[2]; const bf16_t* gb[2]; int loff[2];
    for (int i = 0; i < 2; ++i) {
        const int q = wave * 2 + i;
        const int seg = q & 3, half = q >> 2;
        const int row = half * 64 + lane;
        long ar = min((long)(m0 + row), (long)M - 1);
        long br = min((long)(n0 + row), (long)N - 1);
        ga[i] = A + ar * lda + seg * 8;
        gb[i] = B + br * ldb + seg * 8;
        loff[i] = seg * 1024 + half * 512;
    }
    const bf16_t* ga2 = nullptr;
    if (xrows) {
        long r2 = min((long)(512 + (lane & 15)), (long)M - 1);
        ga2 = A + r2 * lda + (lane >> 4) * 8;      // lane i -> row 512+(i&15), seg i>>4
    }

    f32x4 acc[4][4] = {};
    f32x4 acc4[4] = {};

    for (int i = 0; i < 2; ++i) {
        ASYNC_COPY16(ga[i], &As[0][loff[i]]);
        ASYNC_COPY16(gb[i], &Bs[0][loff[i]]);
    }
    if (xrows && wave == 0) ASYNC_COPY16(ga2, &As2[0][0]);

    for (int k0 = 0; k0 < K; k0 += 32) {
        const int cur = (k0 >> 5) & 1;
        __syncthreads();
        if (k0 + 32 < K) {
            for (int i = 0; i < 2; ++i) {
                ASYNC_COPY16(ga[i] + k0 + 32, &As[cur ^ 1][loff[i]]);
                ASYNC_COPY16(gb[i] + k0 + 32, &Bs[cur ^ 1][loff[i]]);
            }
            if (xrows && wave == 0) ASYNC_COPY16(ga2 + k0 + 32, &As2[cur ^ 1][0]);
        }
        bf16x8 af[4], bfr[4];
        for (int mi = 0; mi < 4; ++mi)
            af[mi] = *(const bf16x8*)&As[cur][quad * 1024 + (wm + mi * 16 + l15) * 8];
        for (int ni = 0; ni < 4; ++ni)
            bfr[ni] = *(const bf16x8*)&Bs[cur][quad * 1024 + (wn + ni * 16 + l15) * 8];
        for (int mi = 0; mi < 4; ++mi)
        for (int ni = 0; ni < 4; ++ni)
            acc[mi][ni] = __builtin_amdgcn_mfma_f32_16x16x32_bf16(af[mi], bfr[ni], acc[mi][ni], 0, 0, 0);
        if (xrows && wm == 64) {
            bf16x8 af4 = *(const bf16x8*)&As2[cur][(quad * 16 + l15) * 8];
            for (int ni = 0; ni < 4; ++ni)
                acc4[ni] = __builtin_amdgcn_mfma_f32_16x16x32_bf16(af4, bfr[ni], acc4[ni], 0, 0, 0);
        }
    }

    for (int mi = 0; mi < 4; ++mi)
    for (int ni = 0; ni < 4; ++ni)
    for (int r = 0; r < 4; ++r) {
        int gm = m0 + wm + mi * 16 + quad * 4 + r;
        int gn = n0 + wn + ni * 16 + l15;
        if (gm >= M || gn >= N) continue;
        C[(long)gm * ldc + gn] = (bf16_t)acc[mi][ni][r];
    }
    if (xrows && wm == 64) {
        for (int ni = 0; ni < 4; ++ni)
        for (int r = 0; r < 4; ++r) {
            int gm = 512 + quad * 4 + r;
            int gn = n0 + wn + ni * 16 + l15;
            if (gm >= M || gn >= N) continue;
            C[(long)gm * ldc + gn] = (bf16_t)acc4[ni][r];
        }
    }
}

// --- f[c0+cl, o2] = max_k lrelu(bn6(C2b[o2, cl*40+k])), bf16 in, padded bf16 out ---
__global__ __launch_bounds__(256)
void epi6_max(const bf16_t* __restrict__ C2b, const float* __restrict__ p6,
              bf16_t* __restrict__ Fb, int c0, int Nc)
{
    const int cl = blockIdx.x, tid = threadIdx.x;
    for (int o2 = tid; o2 < 544; o2 += 256) {
        float r = 0.f;
        if (o2 < 515) {
            const float sc = p6[o2] / sqrtf(p6[3 * 544 + o2] + 1e-5f);
            const float mu = p6[2 * 544 + o2], bb = p6[1 * 544 + o2];
            const bf16x4* p = (const bf16x4*)(C2b + (long)o2 * Nc + cl * 40);  // 8B aligned
            float mx = -__builtin_inff();
            for (int k4 = 0; k4 < 10; ++k4) {
                bf16x4 v = p[k4];
                for (int j = 0; j < 4; ++j) {
                    float h = ((float)v[j] - mu) * sc + bb;
                    h = h >= 0.f ? h : 0.2f * h;
                    mx = fmaxf(mx, h);
                }
            }
            r = mx;
        }
        Fb[(long)(c0 + cl) * 544 + o2] = (bf16_t)r;
    }
}

// ======== 64x64x32 dbuf async GEMM (kNN / T-U) ========
__global__ __launch_bounds__(256)
void gemm64d(const bf16_t* __restrict__ A, const bf16_t* __restrict__ B,
             float* __restrict__ C, const float* __restrict__ xx,
             int M, int N, int K, int lda, int ldb, int ldc,
             long aBS, long bBS, long cBS, int epi, int moff)
{
    __shared__ __align__(16) bf16_t As[2][4 * 64 * 8];
    __shared__ __align__(16) bf16_t Bs[2][4 * 64 * 8];
    const int tid = threadIdx.x;
    const int m0 = blockIdx.y * 64, n0 = blockIdx.x * 64;
    if (epi == 4 && n0 < m0) return;   // symmetric: upper-triangle blocks only
    const int bz = blockIdx.z;
    A += (long)bz * aBS;
    B += (long)bz * bBS;
    const int wave = tid >> 6, lane = tid & 63;
    const int wm = (wave >> 1) * 32, wn = (wave & 1) * 32;
    const int l15 = lane & 15, quad = lane >> 4;

    const long ar = min((long)(m0 + lane), (long)M - 1);
    const long br = min((long)(n0 + lane), (long)N - 1);
    const bf16_t* ga = A + ar * lda + wave * 8;
    const bf16_t* gb = B + br * ldb + wave * 8;

    f32x4 acc[2][2] = {};

    ASYNC_COPY16(ga, &As[0][wave * 512]);
    ASYNC_COPY16(gb, &Bs[0][wave * 512]);

    for (int k0 = 0; k0 < K; k0 += 32) {
        const int cur = (k0 >> 5) & 1;
        __syncthreads();
        if (k0 + 32 < K) {
            ASYNC_COPY16(ga + k0 + 32, &As[cur ^ 1][wave * 512]);
            ASYNC_COPY16(gb + k0 + 32, &Bs[cur ^ 1][wave * 512]);
        }
        bf16x8 af0 = *(const bf16x8*)&As[cur][quad * 512 + (wm +      l15) * 8];
        bf16x8 af1 = *(const bf16x8*)&As[cur][quad * 512 + (wm + 16 + l15) * 8];
        bf16x8 bf0 = *(const bf16x8*)&Bs[cur][quad * 512 + (wn +      l15) * 8];
        bf16x8 bf1 = *(const bf16x8*)&Bs[cur][quad * 512 + (wn + 16 + l15) * 8];
        acc[0][0] = __builtin_amdgcn_mfma_f32_16x16x32_bf16(af0, bf0, acc[0][0], 0, 0, 0);
        acc[0][1] = __builtin_amdgcn_mfma_f32_16x16x32_bf16(af0, bf1, acc[0][1], 0, 0, 0);
        acc[1][0] = __builtin_amdgcn_mfma_f32_16x16x32_bf16(af1, bf0, acc[1][0], 0, 0, 0);
        acc[1][1] = __builtin_amdgcn_mfma_f32_16x16x32_bf16(af1, bf1, acc[1][1], 0, 0, 0);
    }

    C += (long)bz * cBS;
    for (int mi = 0; mi < 2; ++mi)
    for (int ni = 0; ni < 2; ++ni)
    for (int r = 0; r < 4; ++r) {
        int gm = m0 + wm + mi * 16 + quad * 4 + r;
        int gn = n0 + wn + ni * 16 + l15;
        if (gm >= M || gn >= N) continue;
        float o = acc[mi][ni][r];
        if (epi == 4) {
            float v = 2.f * o - xx[gm] - xx[gn];
            C[(long)gm * ldc + gn] = v;
            C[(long)gn * ldc + gm] = v;
        } else if (epi == 1) {
            C[(long)gm * ldc + gn] = 2.f * o - xx[gm + moff] - xx[gn];
        } else {
            C[(long)gm * ldc + gn] = o;
        }
    }
}

// ---------------- 64-tile sync NT GEMM (small mats / rich epilogues) ----------------
__global__ __launch_bounds__(256)
void gemm_nt(const bf16_t* __restrict__ A, const bf16_t* __restrict__ B,
             void* __restrict__ Cv, const float* __restrict__ bias,
             const int* __restrict__ oflag, float alpha,
             int M, int N, int K, int lda, int ldb, int ldc,
             long aBS, long bBS, long cBS, int epi)
{
    __shared__ __align__(16) bf16_t As[64 * 40];
    __shared__ __align__(16) bf16_t Bs[64 * 40];
    const int tid = threadIdx.x;
    const int m0 = blockIdx.y * 64, n0 = blockIdx.x * 64;
    const int bz = blockIdx.z;
    A += (long)bz * aBS;
    B += (long)bz * bBS;

    const int lrow = tid >> 2;
    const int lseg = (tid & 3) * 8;
    const long arow = min(m0 + lrow, M - 1);
    const long brow = min(n0 + lrow, N - 1);
    const bf16_t* ap = A + arow * lda + lseg;
    const bf16_t* bp = B + brow * ldb + lseg;

    const int wave = tid >> 6, lane = tid & 63;
    const int wm = (wave >> 1) * 32, wn = (wave & 1) * 32;
    const int l15 = lane & 15, quad = lane >> 4;

    f32x4 acc[2][2] = {};

    for (int k0 = 0; k0 < K; k0 += 32) {
        int4 av = *(const int4*)ap;  ap += 32;
        int4 bv = *(const int4*)bp;  bp += 32;
        __syncthreads();
        *(int4*)(&As[lrow * 40 + lseg]) = av;
        *(int4*)(&Bs[lrow * 40 + lseg]) = bv;
        __syncthreads();
        bf16x8 af0 = *(const bf16x8*)(&As[(wm +      l15) * 40 + quad * 8]);
        bf16x8 af1 = *(const bf16x8*)(&As[(wm + 16 + l15) * 40 + quad * 8]);
        bf16x8 bf0 = *(const bf16x8*)(&Bs[(wn +      l15) * 40 + quad * 8]);
        bf16x8 bf1 = *(const bf16x8*)(&Bs[(wn + 16 + l15) * 40 + quad * 8]);
        acc[0][0] = __builtin_amdgcn_mfma_f32_16x16x32_bf16(af0, bf0, acc[0][0], 0, 0, 0);
        acc[0][1] = __builtin_amdgcn_mfma_f32_16x16x32_bf16(af0, bf1, acc[0][1], 0, 0, 0);
        acc[1][0] = __builtin_amdgcn_mfma_f32_16x16x32_bf16(af1, bf0, acc[1][0], 0, 0, 0);
        acc[1][1] = __builtin_amdgcn_mfma_f32_16x16x32_bf16(af1, bf1, acc[1][1], 0, 0, 0);
    }

    const int ofl = oflag ? *oflag : 1;
    for (int mi = 0; mi < 2; ++mi)
    for (int ni = 0; ni < 2; ++ni)
    for (int r = 0; r < 4; ++r) {
        int gm = m0 + wm + mi * 16 + quad * 4 + r;
        int gn = n0 + wn + ni * 16 + l15;
        if (gm >= M || gn >= N) continue;
        float o = acc[mi][ni][r];
        long cidx = (long)bz * cBS + (long)gm * ldc + gn;
        switch (epi) {
        case 2: ((bf16_t*)Cv)[cidx] = (bf16_t)o; break;
        case 3: ((float*)Cv)[cidx] = o * alpha; break;
        case 5: ((bf16_t*)Cv)[(long)bz * cBS + (long)gn * ldc + gm] = (bf16_t)o; break;
        case 6: {
            float w = o + bias[gn];
            if (ofl) ((bf16_t*)Cv)[cidx] = (bf16_t)w;
            else     ((float*)Cv)[cidx]  = w;
        } break;
        }
    }
}

// ======== binary-search top-40, SORTED emission (matches lax.top_k order exactly) ========
__global__ __launch_bounds__(256)
void topk40_bs(const float* __restrict__ S, int* __restrict__ idx_out)
{
    __shared__ int red[4];
    __shared__ unsigned long long tmask[8][4];
    __shared__ int sh_slot;
    __shared__ unsigned cu[48];
    __shared__ int      ci[48];
    const int row = blockIdx.x, tid = threadIdx.x;
    const int wave = tid >> 6, lane = tid & 63;

    unsigned uvr[8];
    for (int c = 0; c < 8; ++c) {
        unsigned x = __float_as_uint(S[(long)row * 2048 + c * 256 + tid]);
        uvr[c] = (x & 0x80000000u) ? ~x : (x | 0x80000000u);
    }
    if (tid == 0) sh_slot = 0;

    unsigned lo = 0u, hi = 0xFFFFFFFFu;
    while (hi - lo > 1u) {
        unsigned mid = lo + ((hi - lo) >> 1);
        int c = 0;
        for (int i = 0; i < 8; ++i) c += (uvr[i] > mid) ? 1 : 0;
        for (int o = 32; o; o >>= 1) c += __shfl_down(c, o);
        if (lane == 0) red[wave] = c;
        __syncthreads();
        int tot = red[0] + red[1] + red[2] + red[3];
        __syncthreads();
        if (tot >= 40) lo = mid; else hi = mid;
    }
    const unsigned thr = hi;

    for (int c = 0; c < 8; ++c)
        if (uvr[c] > thr) {
            int s = atomicAdd(&sh_slot, 1);
            cu[s] = uvr[c]; ci[s] = c * 256 + tid;
        }
    for (int c = 0; c < 8; ++c) {
        unsigned long long m = __ballot(uvr[c] == thr);
        if (lane == 0) tmask[c][wave] = m;
    }
    __syncthreads();
    const int want = 40 - sh_slot;
    int base = 0;
    for (int c = 0; c < 8; ++c) {
        if (uvr[c] == thr) {
            int r = base;
            for (int w = 0; w < wave; ++w) r += __popcll(tmask[c][w]);
            r += __popcll(tmask[c][wave] & (((unsigned long long)1 << lane) - 1));
            if (r < want) {
                int s = atomicAdd(&sh_slot, 1);
                cu[s] = uvr[c]; ci[s] = c * 256 + tid;
            }
        }
        for (int w = 0; w < 4; ++w) base += __popcll(tmask[c][w]);
    }
    __syncthreads();
    if (tid < 40) {
        unsigned u = cu[tid]; int i = ci[tid];
        int r = 0;
        for (int j = 0; j < 40; ++j)
            r += (cu[j] > u || (cu[j] == u && ci[j] < i)) ? 1 : 0;
        idx_out[row * 40 + r] = i;
    }
}

// --- H-chunk: Hc[((c5-c0)*40+k)*2048+n] = bf16(lrelu(bn5(T[c5,idx[n,k]] + (U-T)[c5,n]))) ---
__global__ __launch_bounds__(256)
void h1a_gen(const float* __restrict__ T, const float* __restrict__ U,
             const int* __restrict__ idx, const float* __restrict__ pf,
             bf16_t* __restrict__ Hc, int c0)
{
    __shared__ int idxs[40 * 256];
    const int c5 = c0 + blockIdx.y, n0 = blockIdx.x * 256, tid = threadIdx.x;
    for (int i = tid; i < 40 * 256; i += 256)
        idxs[(i % 40) * 256 + (i / 40)] = idx[n0 * 40 + i] & 2047;
    const float sc = pf[c5] / sqrtf(pf[3 * 544 + c5] + 1e-5f);
    const float mu = pf[2 * 544 + c5], bb = pf[1 * 544 + c5];
    const float q  = U[(long)c5 * 2048 + n0 + tid] - T[(long)c5 * 2048 + n0 + tid];
    const float* Trow = T + (long)c5 * 2048;
    __syncthreads();
    for (int k = 0; k < 40; ++k) {
        float h = Trow[idxs[k * 256 + tid]] + q;
        h = (h - mu) * sc + bb;
        h = h >= 0.f ? h : 0.2f * h;
        Hc[(long)(blockIdx.y * 40 + k) * 2048 + n0 + tid] = (bf16_t)h;
    }
}

__global__ __launch_bounds__(256)
void softmax_row(const float* __restrict__ Sc, bf16_t* __restrict__ P)
{
    __shared__ float red[4];
    const long r = blockIdx.x;
    const int tid = threadIdx.x, lane = tid & 63, wave = tid >> 6;
    const float* row = Sc + r * 512;
    float v0 = row[tid], v1 = row[tid + 256];
    float mx = fmaxf(v0, v1);
    for (int off = 32; off; off >>= 1) mx = fmaxf(mx, __shfl_down(mx, off));
    if (lane == 0) red[wave] = mx;
    __syncthreads();
    mx = fmaxf(fmaxf(red[0], red[1]), fmaxf(red[2], red[3]));
    __syncthreads();
    float e0 = expf(v0 - mx), e1 = expf(v1 - mx);
    float sm = e0 + e1;
    for (int off = 32; off; off >>= 1) sm += __shfl_down(sm, off);
    if (lane == 0) red[wave] = sm;
    __syncthreads();
    sm = red[0] + red[1] + red[2] + red[3];
    float inv = 1.f / sm;
    P[r * 512 + tid] = (bf16_t)(e0 * inv);
    P[r * 512 + tid + 256] = (bf16_t)(e1 * inv);
}

extern "C" void kernel_launch(void* const* d_in, const int* in_sizes, int n_in,
                              void* d_out, int out_size, void* d_ws, size_t ws_size,
                              hipStream_t stream)
{
    (void)n_in; (void)out_size;

    char* wsb = (char*)d_ws;
    size_t pos = 0;
    auto alloc = [&](size_t bytes) -> char* {
        char* p = wsb + pos;
        pos += (bytes + 255) & ~(size_t)255;
        return p;
    };
    int*    flags = (int*)  alloc(256);
    int*    idx   = (int*)  alloc(2048 * 40 * 4);
    float*  xx    = (float*)alloc(2048 * 4);
    float*  T     = (float*)alloc((size_t)512 * 2048 * 4);   // U follows contiguously
    float*  U     = (float*)alloc((size_t)512 * 2048 * 4);
    bf16_t* XtA   = (bf16_t*)alloc((size_t)2048 * 1536 * 2);
    bf16_t* XtB   = (bf16_t*)alloc((size_t)2048 * 1536 * 2);
    bf16_t* W5c   = (bf16_t*)alloc((size_t)512 * 1024 * 2);
    bf16_t* W6c   = (bf16_t*)alloc((size_t)515 * 2048 * 2);
    bf16_t* Woutc = (bf16_t*)alloc((size_t)515 * 512 * 2);
    bf16_t* Wqp   = (bf16_t*)alloc((size_t)512 * 544 * 2);
    bf16_t* Wkp   = (bf16_t*)alloc((size_t)512 * 544 * 2);
    bf16_t* Wvp   = (bf16_t*)alloc((size_t)512 * 544 * 2);
    float*  pf    = (float*)alloc((size_t)9 * 544 * 4);
    bf16_t* Fb[2];
    Fb[0] = (bf16_t*)alloc((size_t)512 * 544 * 2);
    Fb[1] = (bf16_t*)alloc((size_t)512 * 544 * 2);
    bf16_t* qb = (bf16_t*)alloc((size_t)512 * 512 * 2);
    bf16_t* kb = (bf16_t*)alloc((size_t)512 * 512 * 2);
    bf16_t* vt = (bf16_t*)alloc((size_t)512 * 512 * 2);
    bf16_t* mg = (bf16_t*)alloc((size_t)512 * 512 * 2);
    char* BIG = wsb + pos;
    size_t big = (ws_size > pos) ? (ws_size - pos) : 0;
    if (big < 3939840) return;

    // conv6 tiers: Hc (CC*40*2048*2 B) + C2b bf16 (515*CC*40*2 B) = CC*205040 B
    const int CC = (big >= 105000000) ? 512 : (big >= 52500000) ? 256
                 : (big >= 26250000)  ? 128 : (big >= 13130000) ? 64
                 : (big >= 6570000)   ? 32  : 16;
    const int RC = (big >= 16777216) ? 2048 : (big >= 4194304) ? 512 : 128;
    const int AH = (big >= 12582912) ? 8 : 1;
    const int Nc = CC * 40;

    float*  S   = (float*)BIG;
    bf16_t* Hc  = (bf16_t*)BIG;
    bf16_t* C2b = (bf16_t*)(BIG + (size_t)Nc * 2048 * 2);
    float*  scA = (float*)BIG;
    bf16_t* prA = (bf16_t*)(BIG + (size_t)AH * 512 * 512 * 4);

    detect_dtype<<<1, 256, 0, stream>>>(d_in[0], in_sizes[0], flags);
    C3 c3;
    c3.p[0] = d_in[2];  c3.d[0] = W5c;   c3.n[0] = 512 * 1024;
    c3.p[1] = d_in[7];  c3.d[1] = W6c;   c3.n[1] = 515 * 2048;
    c3.p[2] = d_in[15]; c3.d[2] = Woutc; c3.n[2] = 515 * 512;
    conv_elem3<<<dim3(512, 1, 3), 256, 0, stream>>>(c3, flags);
    P3 p3;
    p3.p[0] = d_in[12]; p3.p[1] = d_in[13]; p3.p[2] = d_in[14];
    pad_wf3<<<dim3(1088, 1, 3), 256, 0, stream>>>(p3, Wqp, flags);
    P9 pk;
    const int pidx[9] = {3, 4, 5, 6, 8, 9, 10, 11, 16};
    for (int i = 0; i < 9; ++i) { pk.p[i] = d_in[pidx[i]]; pk.n[i] = in_sizes[pidx[i]]; }
    conv_param<<<9, 256, 0, stream>>>(pk, pf, flags);

    for (int b = 0; b < 2; ++b) {
        transpose_split<<<dim3(64, 16), 256, 0, stream>>>(d_in[b], XtA, XtB, flags);
        xx_kernel<<<8, 256, 0, stream>>>(XtA, xx);
        if (RC == 2048) {
            gemm64d<<<dim3(32, 32), 256, 0, stream>>>(XtA, XtB, S,
                xx, 2048, 2048, 1536, 1536, 1536, 2048, 0, 0, 0, 4, 0);
            topk40_bs<<<2048, 256, 0, stream>>>(S, idx);
        } else {
            for (int r0 = 0; r0 < 2048; r0 += RC) {
                gemm64d<<<dim3(32, RC / 64), 256, 0, stream>>>(XtA + (size_t)r0 * 1536, XtB, S,
                    xx, RC, 2048, 1536, 1536, 1536, 2048, 0, 0, 0, 1, r0);
                topk40_bs<<<RC, 256, 0, stream>>>(S, idx + (size_t)r0 * 40);
            }
        }
        gemm64d<<<dim3(32, 8, 2), 256, 0, stream>>>(W5c, XtA, T, nullptr,
            512, 2048, 512, 1024, 1536, 2048, 512, 0, (long)512 * 2048, 0, 0);
        for (int c0 = 0; c0 < 512; c0 += CC) {
            h1a_gen<<<dim3(8, CC), 256, 0, stream>>>(T, U, idx, pf, Hc, c0);
            // conv6: grid (4 m-tiles, Nc/128 n-tiles); Nc/128 multiple of 8 -> swizzle on
            gemm128d<<<dim3(4, Nc / 128), 256, 0, stream>>>(W6c, Hc, C2b,
                515, Nc, 2048, 2048, 2048, Nc);
            epi6_max<<<CC, 256, 0, stream>>>(C2b, pf + 4 * 544, Fb[b], c0, Nc);
        }
    }

    gemm_nt<<<dim3(8, 8, 2), 256, 0, stream>>>(Fb[0], Wqp, qb, nullptr, nullptr, 0.f,
        512, 512, 544, 544, 544, 512,
        (long)512 * 544, (long)512 * 544, (long)512 * 512, 2);
    gemm_nt<<<dim3(8, 8, 1), 256, 0, stream>>>(Fb[1], Wvp, vt, nullptr, nullptr, 0.f,
        512, 512, 544, 544, 544, 512, 0, 0, 0, 5);

    const float SCALE = 0.04419417382415922f;  // 512^-0.5
    if (AH == 8) {
        gemm_nt<<<dim3(8, 8, 8), 256, 0, stream>>>(qb, kb, scA, nullptr, nullptr, SCALE,
            512, 512, 64, 512, 512, 512, 64, 64, 262144, 3);
        softmax_row<<<4096, 256, 0, stream>>>(scA, prA);
        gemm_nt<<<dim3(1, 8, 8), 256, 0, stream>>>(prA, vt, mg, nullptr, nullptr, 0.f,
            512, 64, 512, 512, 512, 512, 262144, 32768, 64, 2);
    } else {
        for (int h = 0; h < 8; ++h) {
            gemm_nt<<<dim3(8, 8, 1), 256, 0, stream>>>(qb + h * 64, kb + h * 64, scA,
                nullptr, nullptr, SCALE, 512, 512, 64, 512, 512, 512, 0, 0, 0, 3);
            softmax_row<<<512, 256, 0, stream>>>(scA, prA);
            gemm_nt<<<dim3(1, 8, 1), 256, 0, stream>>>(prA, vt + (size_t)h * 64 * 512,
                mg + h * 64, nullptr, nullptr, 0.f,
                512, 64, 512, 512, 512, 512, 0, 0, 0, 2);
        }
    }
    gemm_nt<<<dim3(9, 8, 1), 256, 0, stream>>>(mg, Woutc, d_out, pf + 8 * 544, flags,
        0.f, 512, 515, 512, 512, 512, 515, 0, 0, 0, 6);
}

// Round 14
// 828.370 us; speedup vs baseline: 1.1717x; 1.0529x over previous
//
#include <hip/hip_runtime.h>
#include <hip/hip_bf16.h>

typedef __bf16 bf16_t;
typedef float f32x4 __attribute__((ext_vector_type(4)));
typedef __bf16 bf16x8 __attribute__((ext_vector_type(8)));
typedef __bf16 bf16x4 __attribute__((ext_vector_type(4)));

#define ASYNC_COPY16(gptr, lptr) \
    __builtin_amdgcn_global_load_lds((const __attribute__((address_space(1))) void*)(gptr), \
                                     (__attribute__((address_space(3))) void*)(lptr), 16, 0, 0)

__device__ __forceinline__ float ldx(const void* p, long i, int isbf) {
    return isbf ? (float)((const bf16_t*)p)[i] : ((const float*)p)[i];
}

// ---------------- dtype probe ----------------
__global__ __launch_bounds__(256)
void detect_dtype(const void* __restrict__ x, int n, int* __restrict__ flags)
{
    __shared__ int red[4];
    const int tid = threadIdx.x;
    const int ns = n < 8192 ? n : 8192;
    int cnt = 0;
    for (int i = tid; i < ns; i += 256) {
        float v = (float)((const bf16_t*)x)[i];
        float a = fabsf(v);
        bool pl = (v == 0.f) || (a >= 6e-8f && a <= 1.7e7f);
        cnt += pl ? 1 : 0;
    }
    for (int o = 32; o; o >>= 1) cnt += __shfl_down(cnt, o);
    if ((tid & 63) == 0) red[tid >> 6] = cnt;
    __syncthreads();
    if (tid == 0) {
        int t = red[0] + red[1] + red[2] + red[3];
        flags[0] = (t * 10 >= ns * 9) ? 1 : 0;
    }
}

struct C3 { const void* p[3]; bf16_t* d[3]; int n[3]; };
__global__ __launch_bounds__(256)
void conv_elem3(C3 c, const int* __restrict__ flag)
{
    const int isbf = *flag;
    const int z = blockIdx.z, n = c.n[z];
    bf16_t* dst = c.d[z];
    const void* src = c.p[z];
    for (long i = blockIdx.x * 256L + threadIdx.x; i < n; i += (long)gridDim.x * 256)
        dst[i] = (bf16_t)ldx(src, i, isbf);
}

struct P9 { const void* p[9]; int n[9]; };
__global__ __launch_bounds__(256)
void conv_param(P9 pk, float* __restrict__ dst, const int* __restrict__ flag)
{
    const int isbf = *flag;
    const int b = blockIdx.x, n = pk.n[b];
    for (int j = threadIdx.x; j < n; j += 256)
        dst[b * 544 + j] = ldx(pk.p[b], j, isbf);
}

struct P3 { const void* p[3]; };
__global__ __launch_bounds__(256)
void pad_wf3(P3 ps, bf16_t* __restrict__ Wp0, const int* __restrict__ flag)
{
    const int isbf = *flag;
    const int z = blockIdx.z;
    const long i = blockIdx.x * 256L + threadIdx.x;
    if (i >= 512 * 544) return;
    const long o = i / 544, c = i % 544;
    bf16_t* Wp = Wp0 + (size_t)z * 512 * 544;
    Wp[i] = (c < 515) ? (bf16_t)ldx(ps.p[z], o * 515 + c, isbf) : (bf16_t)0.f;
}

// ---- X (512x2048) -> XtA[n][hi|lo|hi], XtB[n][hi|hi|lo] (2048x1536 bf16) ----
__global__ __launch_bounds__(256)
void transpose_split(const void* __restrict__ X, bf16_t* __restrict__ XtA,
                     bf16_t* __restrict__ XtB, const int* __restrict__ flag)
{
    __shared__ __align__(16) bf16_t thi[32][33];
    __shared__ __align__(16) bf16_t tlo[32][33];
    const int isbf = *flag;
    const int n0 = blockIdx.x * 32, c0 = blockIdx.y * 32;
    const int lx = threadIdx.x & 31, ly = threadIdx.x >> 5;
    for (int i = 0; i < 4; ++i) {
        float v = ldx(X, (long)(c0 + ly + i * 8) * 2048 + n0 + lx, isbf);
        bf16_t hi = (bf16_t)v;
        thi[ly + i * 8][lx] = hi;
        tlo[ly + i * 8][lx] = (bf16_t)(v - (float)hi);
    }
    __syncthreads();
    for (int i = 0; i < 4; ++i) {
        const long n = n0 + ly + i * 8;
        const int c = c0 + lx;
        bf16_t hi = thi[lx][ly + i * 8], lo = tlo[lx][ly + i * 8];
        XtA[n * 1536 + c] = hi;  XtA[n * 1536 + 512 + c] = lo;  XtA[n * 1536 + 1024 + c] = hi;
        XtB[n * 1536 + c] = hi;  XtB[n * 1536 + 512 + c] = hi;  XtB[n * 1536 + 1024 + c] = lo;
    }
}

__global__ __launch_bounds__(256)
void xx_kernel(const bf16_t* __restrict__ XtA, float* __restrict__ xx)
{
    const long n = blockIdx.x * 256L + threadIdx.x;
    float acc = 0.f;
    for (int c = 0; c < 512; ++c) {
        float v = (float)XtA[n * 1536 + c] + (float)XtA[n * 1536 + 512 + c];
        acc += v * v;
    }
    xx[n] = acc;
}

// ======== conv6: 128x128x32 dbuf LDS GEMM, XCD-swizzled, M-trimmed, bf16 out ========
// Grid x = 4 m-tiles (rows 0-511; no dead 5th tile). Tail rows 512-514: mt==3/wm==64
// waves read the A-fragment DIRECTLY from global (W6 tail = 12 KB, L2-hot, 160 blocks)
// -- no extra LDS, so LDS stays 32768 B -> 5 blocks/CU (R13's As2 pushed 34.8 KB -> 4
// blocks/CU and cancelled the block win). Same MFMA sequence -> bit-identical C2.
__global__ __launch_bounds__(256)
void gemm128d(const bf16_t* __restrict__ A, const bf16_t* __restrict__ B,
              bf16_t* __restrict__ C, int M, int N, int K, int lda, int ldb, int ldc)
{
    __shared__ __align__(16) bf16_t As[2][4096];   // [stage][seg(4)][row(128)][8]
    __shared__ __align__(16) bf16_t Bs[2][4096];
    const int tid = threadIdx.x;
    int mt, nt;
    {   // XCD swizzle (proven R9/R10: FETCH 250->73 MB): gridDim.y multiple of 8
        const int bid = blockIdx.y * gridDim.x + blockIdx.x;
        const int xcd = bid & 7, s = bid >> 3;
        mt = s % gridDim.x;
        nt = xcd + 8 * (s / gridDim.x);
    }
    const int m0 = mt * 128, n0 = nt * 128;
    const int wave = tid >> 6, lane = tid & 63;
    const int wm = (wave >> 1) * 64, wn = (wave & 1) * 64;
    const int l15 = lane & 15, quad = lane >> 4;
    const bool tail = (mt == 3) && (wm == 64);     // wave computes rows 512..514 too

    const bf16_t* ga[2]; const bf16_t* gb[2]; int loff[2];
    for (int i = 0; i < 2; ++i) {
        const int q = wave * 2 + i;
        const int seg = q & 3, half = q >> 2;
        const int row = half * 64 + lane;
        long ar = min((long)(m0 + row), (long)M - 1);
        long br = min((long)(n0 + row), (long)N - 1);
        ga[i] = A + ar * lda + seg * 8;
        gb[i] = B + br * ldb + seg * 8;
        loff[i] = seg * 1024 + half * 512;
    }
    const bf16_t* ga2 = A + min((long)(512 + l15), (long)M - 1) * lda + quad * 8;

    f32x4 acc[4][4] = {};
    f32x4 acc4[4] = {};

    for (int i = 0; i < 2; ++i) {
        ASYNC_COPY16(ga[i], &As[0][loff[i]]);
        ASYNC_COPY16(gb[i], &Bs[0][loff[i]]);
    }

    for (int k0 = 0; k0 < K; k0 += 32) {
        const int cur = (k0 >> 5) & 1;
        __syncthreads();
        if (k0 + 32 < K) {
            for (int i = 0; i < 2; ++i) {
                ASYNC_COPY16(ga[i] + k0 + 32, &As[cur ^ 1][loff[i]]);
                ASYNC_COPY16(gb[i] + k0 + 32, &Bs[cur ^ 1][loff[i]]);
            }
        }
        bf16x8 af[4], bfr[4];
        for (int mi = 0; mi < 4; ++mi)
            af[mi] = *(const bf16x8*)&As[cur][quad * 1024 + (wm + mi * 16 + l15) * 8];
        for (int ni = 0; ni < 4; ++ni)
            bfr[ni] = *(const bf16x8*)&Bs[cur][quad * 1024 + (wn + ni * 16 + l15) * 8];
        for (int mi = 0; mi < 4; ++mi)
        for (int ni = 0; ni < 4; ++ni)
            acc[mi][ni] = __builtin_amdgcn_mfma_f32_16x16x32_bf16(af[mi], bfr[ni], acc[mi][ni], 0, 0, 0);
        if (tail) {
            bf16x8 af4 = *(const bf16x8*)(ga2 + k0);   // global, L2-hot, 16B aligned
            for (int ni = 0; ni < 4; ++ni)
                acc4[ni] = __builtin_amdgcn_mfma_f32_16x16x32_bf16(af4, bfr[ni], acc4[ni], 0, 0, 0);
        }
    }

    for (int mi = 0; mi < 4; ++mi)
    for (int ni = 0; ni < 4; ++ni)
    for (int r = 0; r < 4; ++r) {
        int gm = m0 + wm + mi * 16 + quad * 4 + r;
        int gn = n0 + wn + ni * 16 + l15;
        if (gm >= M || gn >= N) continue;
        C[(long)gm * ldc + gn] = (bf16_t)acc[mi][ni][r];
    }
    if (tail) {
        for (int ni = 0; ni < 4; ++ni)
        for (int r = 0; r < 4; ++r) {
            int gm = 512 + quad * 4 + r;
            int gn = n0 + wn + ni * 16 + l15;
            if (gm >= M || gn >= N) continue;
            C[(long)gm * ldc + gn] = (bf16_t)acc4[ni][r];
        }
    }
}

// --- f[c0+cl, o2] = max_k lrelu(bn6(C2b[o2, cl*40+k])), bf16 in, padded bf16 out ---
__global__ __launch_bounds__(256)
void epi6_max(const bf16_t* __restrict__ C2b, const float* __restrict__ p6,
              bf16_t* __restrict__ Fb, int c0, int Nc)
{
    const int cl = blockIdx.x, tid = threadIdx.x;
    for (int o2 = tid; o2 < 544; o2 += 256) {
        float r = 0.f;
        if (o2 < 515) {
            const float sc = p6[o2] / sqrtf(p6[3 * 544 + o2] + 1e-5f);
            const float mu = p6[2 * 544 + o2], bb = p6[1 * 544 + o2];
            const bf16x4* p = (const bf16x4*)(C2b + (long)o2 * Nc + cl * 40);  // 8B aligned
            float mx = -__builtin_inff();
            for (int k4 = 0; k4 < 10; ++k4) {
                bf16x4 v = p[k4];
                for (int j = 0; j < 4; ++j) {
                    float h = ((float)v[j] - mu) * sc + bb;
                    h = h >= 0.f ? h : 0.2f * h;
                    mx = fmaxf(mx, h);
                }
            }
            r = mx;
        }
        Fb[(long)(c0 + cl) * 544 + o2] = (bf16_t)r;
    }
}

// ======== 64x64x32 dbuf async GEMM (kNN / T-U) ========
__global__ __launch_bounds__(256)
void gemm64d(const bf16_t* __restrict__ A, const bf16_t* __restrict__ B,
             float* __restrict__ C, const float* __restrict__ xx,
             int M, int N, int K, int lda, int ldb, int ldc,
             long aBS, long bBS, long cBS, int epi, int moff)
{
    __shared__ __align__(16) bf16_t As[2][4 * 64 * 8];
    __shared__ __align__(16) bf16_t Bs[2][4 * 64 * 8];
    const int tid = threadIdx.x;
    const int m0 = blockIdx.y * 64, n0 = blockIdx.x * 64;
    if (epi == 4 && n0 < m0) return;   // symmetric: upper-triangle blocks only
    const int bz = blockIdx.z;
    A += (long)bz * aBS;
    B += (long)bz * bBS;
    const int wave = tid >> 6, lane = tid & 63;
    const int wm = (wave >> 1) * 32, wn = (wave & 1) * 32;
    const int l15 = lane & 15, quad = lane >> 4;

    const long ar = min((long)(m0 + lane), (long)M - 1);
    const long br = min((long)(n0 + lane), (long)N - 1);
    const bf16_t* ga = A + ar * lda + wave * 8;
    const bf16_t* gb = B + br * ldb + wave * 8;

    f32x4 acc[2][2] = {};

    ASYNC_COPY16(ga, &As[0][wave * 512]);
    ASYNC_COPY16(gb, &Bs[0][wave * 512]);

    for (int k0 = 0; k0 < K; k0 += 32) {
        const int cur = (k0 >> 5) & 1;
        __syncthreads();
        if (k0 + 32 < K) {
            ASYNC_COPY16(ga + k0 + 32, &As[cur ^ 1][wave * 512]);
            ASYNC_COPY16(gb + k0 + 32, &Bs[cur ^ 1][wave * 512]);
        }
        bf16x8 af0 = *(const bf16x8*)&As[cur][quad * 512 + (wm +      l15) * 8];
        bf16x8 af1 = *(const bf16x8*)&As[cur][quad * 512 + (wm + 16 + l15) * 8];
        bf16x8 bf0 = *(const bf16x8*)&Bs[cur][quad * 512 + (wn +      l15) * 8];
        bf16x8 bf1 = *(const bf16x8*)&Bs[cur][quad * 512 + (wn + 16 + l15) * 8];
        acc[0][0] = __builtin_amdgcn_mfma_f32_16x16x32_bf16(af0, bf0, acc[0][0], 0, 0, 0);
        acc[0][1] = __builtin_amdgcn_mfma_f32_16x16x32_bf16(af0, bf1, acc[0][1], 0, 0, 0);
        acc[1][0] = __builtin_amdgcn_mfma_f32_16x16x32_bf16(af1, bf0, acc[1][0], 0, 0, 0);
        acc[1][1] = __builtin_amdgcn_mfma_f32_16x16x32_bf16(af1, bf1, acc[1][1], 0, 0, 0);
    }

    C += (long)bz * cBS;
    for (int mi = 0; mi < 2; ++mi)
    for (int ni = 0; ni < 2; ++ni)
    for (int r = 0; r < 4; ++r) {
        int gm = m0 + wm + mi * 16 + quad * 4 + r;
        int gn = n0 + wn + ni * 16 + l15;
        if (gm >= M || gn >= N) continue;
        float o = acc[mi][ni][r];
        if (epi == 4) {
            float v = 2.f * o - xx[gm] - xx[gn];
            C[(long)gm * ldc + gn] = v;
            C[(long)gn * ldc + gm] = v;
        } else if (epi == 1) {
            C[(long)gm * ldc + gn] = 2.f * o - xx[gm + moff] - xx[gn];
        } else {
            C[(long)gm * ldc + gn] = o;
        }
    }
}

// ---------------- 64-tile sync NT GEMM (small mats / rich epilogues) ----------------
__global__ __launch_bounds__(256)
void gemm_nt(const bf16_t* __restrict__ A, const bf16_t* __restrict__ B,
             void* __restrict__ Cv, const float* __restrict__ bias,
             const int* __restrict__ oflag, float alpha,
             int M, int N, int K, int lda, int ldb, int ldc,
             long aBS, long bBS, long cBS, int epi)
{
    __shared__ __align__(16) bf16_t As[64 * 40];
    __shared__ __align__(16) bf16_t Bs[64 * 40];
    const int tid = threadIdx.x;
    const int m0 = blockIdx.y * 64, n0 = blockIdx.x * 64;
    const int bz = blockIdx.z;
    A += (long)bz * aBS;
    B += (long)bz * bBS;

    const int lrow = tid >> 2;
    const int lseg = (tid & 3) * 8;
    const long arow = min(m0 + lrow, M - 1);
    const long brow = min(n0 + lrow, N - 1);
    const bf16_t* ap = A + arow * lda + lseg;
    const bf16_t* bp = B + brow * ldb + lseg;

    const int wave = tid >> 6, lane = tid & 63;
    const int wm = (wave >> 1) * 32, wn = (wave & 1) * 32;
    const int l15 = lane & 15, quad = lane >> 4;

    f32x4 acc[2][2] = {};

    for (int k0 = 0; k0 < K; k0 += 32) {
        int4 av = *(const int4*)ap;  ap += 32;
        int4 bv = *(const int4*)bp;  bp += 32;
        __syncthreads();
        *(int4*)(&As[lrow * 40 + lseg]) = av;
        *(int4*)(&Bs[lrow * 40 + lseg]) = bv;
        __syncthreads();
        bf16x8 af0 = *(const bf16x8*)(&As[(wm +      l15) * 40 + quad * 8]);
        bf16x8 af1 = *(const bf16x8*)(&As[(wm + 16 + l15) * 40 + quad * 8]);
        bf16x8 bf0 = *(const bf16x8*)(&Bs[(wn +      l15) * 40 + quad * 8]);
        bf16x8 bf1 = *(const bf16x8*)(&Bs[(wn + 16 + l15) * 40 + quad * 8]);
        acc[0][0] = __builtin_amdgcn_mfma_f32_16x16x32_bf16(af0, bf0, acc[0][0], 0, 0, 0);
        acc[0][1] = __builtin_amdgcn_mfma_f32_16x16x32_bf16(af0, bf1, acc[0][1], 0, 0, 0);
        acc[1][0] = __builtin_amdgcn_mfma_f32_16x16x32_bf16(af1, bf0, acc[1][0], 0, 0, 0);
        acc[1][1] = __builtin_amdgcn_mfma_f32_16x16x32_bf16(af1, bf1, acc[1][1], 0, 0, 0);
    }

    const int ofl = oflag ? *oflag : 1;
    for (int mi = 0; mi < 2; ++mi)
    for (int ni = 0; ni < 2; ++ni)
    for (int r = 0; r < 4; ++r) {
        int gm = m0 + wm + mi * 16 + quad * 4 + r;
        int gn = n0 + wn + ni * 16 + l15;
        if (gm >= M || gn >= N) continue;
        float o = acc[mi][ni][r];
        long cidx = (long)bz * cBS + (long)gm * ldc + gn;
        switch (epi) {
        case 2: ((bf16_t*)Cv)[cidx] = (bf16_t)o; break;
        case 3: ((float*)Cv)[cidx] = o * alpha; break;
        case 5: ((bf16_t*)Cv)[(long)bz * cBS + (long)gn * ldc + gm] = (bf16_t)o; break;
        case 6: {
            float w = o + bias[gn];
            if (ofl) ((bf16_t*)Cv)[cidx] = (bf16_t)w;
            else     ((float*)Cv)[cidx]  = w;
        } break;
        }
    }
}

// ======== binary-search top-40, SORTED emission (matches lax.top_k order exactly) ========
__global__ __launch_bounds__(256)
void topk40_bs(const float* __restrict__ S, int* __restrict__ idx_out)
{
    __shared__ int red[4];
    __shared__ unsigned long long tmask[8][4];
    __shared__ int sh_slot;
    __shared__ unsigned cu[48];
    __shared__ int      ci[48];
    const int row = blockIdx.x, tid = threadIdx.x;
    const int wave = tid >> 6, lane = tid & 63;

    unsigned uvr[8];
    for (int c = 0; c < 8; ++c) {
        unsigned x = __float_as_uint(S[(long)row * 2048 + c * 256 + tid]);
        uvr[c] = (x & 0x80000000u) ? ~x : (x | 0x80000000u);
    }
    if (tid == 0) sh_slot = 0;

    unsigned lo = 0u, hi = 0xFFFFFFFFu;
    while (hi - lo > 1u) {
        unsigned mid = lo + ((hi - lo) >> 1);
        int c = 0;
        for (int i = 0; i < 8; ++i) c += (uvr[i] > mid) ? 1 : 0;
        for (int o = 32; o; o >>= 1) c += __shfl_down(c, o);
        if (lane == 0) red[wave] = c;
        __syncthreads();
        int tot = red[0] + red[1] + red[2] + red[3];
        __syncthreads();
        if (tot >= 40) lo = mid; else hi = mid;
    }
    const unsigned thr = hi;

    for (int c = 0; c < 8; ++c)
        if (uvr[c] > thr) {
            int s = atomicAdd(&sh_slot, 1);
            cu[s] = uvr[c]; ci[s] = c * 256 + tid;
        }
    for (int c = 0; c < 8; ++c) {
        unsigned long long m = __ballot(uvr[c] == thr);
        if (lane == 0) tmask[c][wave] = m;
    }
    __syncthreads();
    const int want = 40 - sh_slot;
    int base = 0;
    for (int c = 0; c < 8; ++c) {
        if (uvr[c] == thr) {
            int r = base;
            for (int w = 0; w < wave; ++w) r += __popcll(tmask[c][w]);
            r += __popcll(tmask[c][wave] & (((unsigned long long)1 << lane) - 1));
            if (r < want) {
                int s = atomicAdd(&sh_slot, 1);
                cu[s] = uvr[c]; ci[s] = c * 256 + tid;
            }
        }
        for (int w = 0; w < 4; ++w) base += __popcll(tmask[c][w]);
    }
    __syncthreads();
    if (tid < 40) {
        unsigned u = cu[tid]; int i = ci[tid];
        int r = 0;
        for (int j = 0; j < 40; ++j)
            r += (cu[j] > u || (cu[j] == u && ci[j] < i)) ? 1 : 0;
        idx_out[row * 40 + r] = i;
    }
}

// --- H-chunk: Hc[((c5-c0)*40+k)*2048+n] = bf16(lrelu(bn5(T[c5,idx[n,k]] + (U-T)[c5,n]))) ---
__global__ __launch_bounds__(256)
void h1a_gen(const float* __restrict__ T, const float* __restrict__ U,
             const int* __restrict__ idx, const float* __restrict__ pf,
             bf16_t* __restrict__ Hc, int c0)
{
    __shared__ int idxs[40 * 256];
    const int c5 = c0 + blockIdx.y, n0 = blockIdx.x * 256, tid = threadIdx.x;
    for (int i = tid; i < 40 * 256; i += 256)
        idxs[(i % 40) * 256 + (i / 40)] = idx[n0 * 40 + i] & 2047;
    const float sc = pf[c5] / sqrtf(pf[3 * 544 + c5] + 1e-5f);
    const float mu = pf[2 * 544 + c5], bb = pf[1 * 544 + c5];
    const float q  = U[(long)c5 * 2048 + n0 + tid] - T[(long)c5 * 2048 + n0 + tid];
    const float* Trow = T + (long)c5 * 2048;
    __syncthreads();
    for (int k = 0; k < 40; ++k) {
        float h = Trow[idxs[k * 256 + tid]] + q;
        h = (h - mu) * sc + bb;
        h = h >= 0.f ? h : 0.2f * h;
        Hc[(long)(blockIdx.y * 40 + k) * 2048 + n0 + tid] = (bf16_t)h;
    }
}

__global__ __launch_bounds__(256)
void softmax_row(const float* __restrict__ Sc, bf16_t* __restrict__ P)
{
    __shared__ float red[4];
    const long r = blockIdx.x;
    const int tid = threadIdx.x, lane = tid & 63, wave = tid >> 6;
    const float* row = Sc + r * 512;
    float v0 = row[tid], v1 = row[tid + 256];
    float mx = fmaxf(v0, v1);
    for (int off = 32; off; off >>= 1) mx = fmaxf(mx, __shfl_down(mx, off));
    if (lane == 0) red[wave] = mx;
    __syncthreads();
    mx = fmaxf(fmaxf(red[0], red[1]), fmaxf(red[2], red[3]));
    __syncthreads();
    float e0 = expf(v0 - mx), e1 = expf(v1 - mx);
    float sm = e0 + e1;
    for (int off = 32; off; off >>= 1) sm += __shfl_down(sm, off);
    if (lane == 0) red[wave] = sm;
    __syncthreads();
    sm = red[0] + red[1] + red[2] + red[3];
    float inv = 1.f / sm;
    P[r * 512 + tid] = (bf16_t)(e0 * inv);
    P[r * 512 + tid + 256] = (bf16_t)(e1 * inv);
}

extern "C" void kernel_launch(void* const* d_in, const int* in_sizes, int n_in,
                              void* d_out, int out_size, void* d_ws, size_t ws_size,
                              hipStream_t stream)
{
    (void)n_in; (void)out_size;

    char* wsb = (char*)d_ws;
    size_t pos = 0;
    auto alloc = [&](size_t bytes) -> char* {
        char* p = wsb + pos;
        pos += (bytes + 255) & ~(size_t)255;
        return p;
    };
    int*    flags = (int*)  alloc(256);
    int*    idx   = (int*)  alloc(2048 * 40 * 4);
    float*  xx    = (float*)alloc(2048 * 4);
    float*  T     = (float*)alloc((size_t)512 * 2048 * 4);   // U follows contiguously
    float*  U     = (float*)alloc((size_t)512 * 2048 * 4);
    bf16_t* XtA   = (bf16_t*)alloc((size_t)2048 * 1536 * 2);
    bf16_t* XtB   = (bf16_t*)alloc((size_t)2048 * 1536 * 2);
    bf16_t* W5c   = (bf16_t*)alloc((size_t)512 * 1024 * 2);
    bf16_t* W6c   = (bf16_t*)alloc((size_t)515 * 2048 * 2);
    bf16_t* Woutc = (bf16_t*)alloc((size_t)515 * 512 * 2);
    bf16_t* Wqp   = (bf16_t*)alloc((size_t)512 * 544 * 2);
    bf16_t* Wkp   = (bf16_t*)alloc((size_t)512 * 544 * 2);
    bf16_t* Wvp   = (bf16_t*)alloc((size_t)512 * 544 * 2);
    float*  pf    = (float*)alloc((size_t)9 * 544 * 4);
    bf16_t* Fb[2];
    Fb[0] = (bf16_t*)alloc((size_t)512 * 544 * 2);
    Fb[1] = (bf16_t*)alloc((size_t)512 * 544 * 2);
    bf16_t* qb = (bf16_t*)alloc((size_t)512 * 512 * 2);
    bf16_t* kb = (bf16_t*)alloc((size_t)512 * 512 * 2);
    bf16_t* vt = (bf16_t*)alloc((size_t)512 * 512 * 2);
    bf16_t* mg = (bf16_t*)alloc((size_t)512 * 512 * 2);
    char* BIG = wsb + pos;
    size_t big = (ws_size > pos) ? (ws_size - pos) : 0;
    if (big < 3939840) return;

    // conv6 tiers: Hc (CC*40*2048*2 B) + C2b bf16 (515*CC*40*2 B)
    const int CC = (big >= 105000000) ? 512 : (big >= 52500000) ? 256
                 : (big >= 26250000)  ? 128 : (big >= 13130000) ? 64
                 : (big >= 6570000)   ? 32  : 16;
    const int RC = (big >= 16777216) ? 2048 : (big >= 4194304) ? 512 : 128;
    const int AH = (big >= 12582912) ? 8 : 1;
    const int Nc = CC * 40;

    float*  S   = (float*)BIG;
    bf16_t* Hc  = (bf16_t*)BIG;
    bf16_t* C2b = (bf16_t*)(BIG + (size_t)Nc * 2048 * 2);
    float*  scA = (float*)BIG;
    bf16_t* prA = (bf16_t*)(BIG + (size_t)AH * 512 * 512 * 4);

    detect_dtype<<<1, 256, 0, stream>>>(d_in[0], in_sizes[0], flags);
    C3 c3;
    c3.p[0] = d_in[2];  c3.d[0] = W5c;   c3.n[0] = 512 * 1024;
    c3.p[1] = d_in[7];  c3.d[1] = W6c;   c3.n[1] = 515 * 2048;
    c3.p[2] = d_in[15]; c3.d[2] = Woutc; c3.n[2] = 515 * 512;
    conv_elem3<<<dim3(512, 1, 3), 256, 0, stream>>>(c3, flags);
    P3 p3;
    p3.p[0] = d_in[12]; p3.p[1] = d_in[13]; p3.p[2] = d_in[14];
    pad_wf3<<<dim3(1088, 1, 3), 256, 0, stream>>>(p3, Wqp, flags);
    P9 pk;
    const int pidx[9] = {3, 4, 5, 6, 8, 9, 10, 11, 16};
    for (int i = 0; i < 9; ++i) { pk.p[i] = d_in[pidx[i]]; pk.n[i] = in_sizes[pidx[i]]; }
    conv_param<<<9, 256, 0, stream>>>(pk, pf, flags);

    for (int b = 0; b < 2; ++b) {
        transpose_split<<<dim3(64, 16), 256, 0, stream>>>(d_in[b], XtA, XtB, flags);
        xx_kernel<<<8, 256, 0, stream>>>(XtA, xx);
        if (RC == 2048) {
            gemm64d<<<dim3(32, 32), 256, 0, stream>>>(XtA, XtB, S,
                xx, 2048, 2048, 1536, 1536, 1536, 2048, 0, 0, 0, 4, 0);
            topk40_bs<<<2048, 256, 0, stream>>>(S, idx);
        } else {
            for (int r0 = 0; r0 < 2048; r0 += RC) {
                gemm64d<<<dim3(32, RC / 64), 256, 0, stream>>>(XtA + (size_t)r0 * 1536, XtB, S,
                    xx, RC, 2048, 1536, 1536, 1536, 2048, 0, 0, 0, 1, r0);
                topk40_bs<<<RC, 256, 0, stream>>>(S, idx + (size_t)r0 * 40);
            }
        }
        gemm64d<<<dim3(32, 8, 2), 256, 0, stream>>>(W5c, XtA, T, nullptr,
            512, 2048, 512, 1024, 1536, 2048, 512, 0, (long)512 * 2048, 0, 0);
        for (int c0 = 0; c0 < 512; c0 += CC) {
            h1a_gen<<<dim3(8, CC), 256, 0, stream>>>(T, U, idx, pf, Hc, c0);
            gemm128d<<<dim3(4, Nc / 128), 256, 0, stream>>>(W6c, Hc, C2b,
                515, Nc, 2048, 2048, 2048, Nc);
            epi6_max<<<CC, 256, 0, stream>>>(C2b, pf + 4 * 544, Fb[b], c0, Nc);
        }
    }

    gemm_nt<<<dim3(8, 8, 2), 256, 0, stream>>>(Fb[0], Wqp, qb, nullptr, nullptr, 0.f,
        512, 512, 544, 544, 544, 512,
        (long)512 * 544, (long)512 * 544, (long)512 * 512, 2);
    gemm_nt<<<dim3(8, 8, 1), 256, 0, stream>>>(Fb[1], Wvp, vt, nullptr, nullptr, 0.f,
        512, 512, 544, 544, 544, 512, 0, 0, 0, 5);

    const float SCALE = 0.04419417382415922f;  // 512^-0.5
    if (AH == 8) {
        gemm_nt<<<dim3(8, 8, 8), 256, 0, stream>>>(qb, kb, scA, nullptr, nullptr, SCALE,
            512, 512, 64, 512, 512, 512, 64, 64, 262144, 3);
        softmax_row<<<4096, 256, 0, stream>>>(scA, prA);
        gemm_nt<<<dim3(1, 8, 8), 256, 0, stream>>>(prA, vt, mg, nullptr, nullptr, 0.f,
            512, 64, 512, 512, 512, 512, 262144, 32768, 64, 2);
    } else {
        for (int h = 0; h < 8; ++h) {
            gemm_nt<<<dim3(8, 8, 1), 256, 0, stream>>>(qb + h * 64, kb + h * 64, scA,
                nullptr, nullptr, SCALE, 512, 512, 64, 512, 512, 512, 0, 0, 0, 3);
            softmax_row<<<512, 256, 0, stream>>>(scA, prA);
            gemm_nt<<<dim3(1, 8, 1), 256, 0, stream>>>(prA, vt + (size_t)h * 64 * 512,
                mg + h * 64, nullptr, nullptr, 0.f,
                512, 64, 512, 512, 512, 512, 0, 0, 0, 2);
        }
    }
    gemm_nt<<<dim3(9, 8, 1), 256, 0, stream>>>(mg, Woutc, d_out, pf + 8 * 544, flags,
        0.f, 512, 515, 512, 512, 512, 515, 0, 0, 0, 6);
}